// Round 1
// baseline (1577.506 us; speedup 1.0000x reference)
//
#include <hip/hip_runtime.h>

// Sparse conv2d, direct fp32 baseline.
// x:     [32, 256, 56, 56] f32
// w_vals:[256, 64, 3, 3]   f32
// w_idx: [256, 64]         i32
// out:   [32, 256, 56, 56] f32
//
// One block per (b, o). Loop over the 64 sparse in-channels; stage each
// 56x56 plane (+1 halo) into LDS; each thread computes a 2x7 output tile.

#define BDIM 256

__global__ __launch_bounds__(BDIM) void sparse_conv_kernel(
    const float* __restrict__ x, const float* __restrict__ wv,
    const int* __restrict__ widx, float* __restrict__ out)
{
    const int bid = blockIdx.x;
    const int b = bid >> 8;      // batch
    const int o = bid & 255;     // out channel (fast index -> same b on an XCD)
    const int tid = threadIdx.x;

    // 58 rows (halo) x stride 60 floats. 2*60 = 120 = 24 mod 32 -> uniform
    // 2-way bank aliasing across the wave (free on CDNA4, m136).
    __shared__ float plane[58 * 60];

    const int rt = tid >> 3;     // 0..31, rows used: 0..27
    const int ct = tid & 7;      // 0..7
    const int r0 = rt * 2;
    const int c0 = ct * 7;
    const bool active = (rt < 28);   // 224 compute threads; all 256 stage

    float acc[2][7];
#pragma unroll
    for (int i = 0; i < 2; ++i)
#pragma unroll
        for (int c = 0; c < 7; ++c) acc[i][c] = 0.f;

    const float* xb  = x + (size_t)b * 256 * 56 * 56;
    const int*   idxp = widx + o * 64;
    const float* wp0  = wv + (size_t)o * 64 * 9;

    for (int j = 0; j < 64; ++j) {
        const int cin = idxp[j];                 // uniform -> scalar load
        const float* src = xb + cin * 56 * 56;

        __syncthreads();                         // guard prev-iter reads
        // Stage 58x58 halo plane; zeros at the borders.
        for (int i = tid; i < 58 * 58; i += BDIM) {
            const int r = i / 58;
            const int c = i - r * 58;
            const int h = r - 1, w = c - 1;
            float v = 0.f;
            if ((unsigned)h < 56u && (unsigned)w < 56u) v = src[h * 56 + w];
            plane[r * 60 + c] = v;
        }
        float wreg[9];
#pragma unroll
        for (int k = 0; k < 9; ++k) wreg[k] = wp0[j * 9 + k];  // uniform
        __syncthreads();

        if (active) {
            // rows r0-1 .. r0+2 (lds rows r0 .. r0+3), cols c0-1 .. c0+7
            float rows[4][9];
#pragma unroll
            for (int dr = 0; dr < 4; ++dr)
#pragma unroll
                for (int cc = 0; cc < 9; ++cc)
                    rows[dr][cc] = plane[(r0 + dr) * 60 + (c0 + cc)];
#pragma unroll
            for (int i = 0; i < 2; ++i)
#pragma unroll
                for (int cc = 0; cc < 7; ++cc) {
                    float s = acc[i][cc];
#pragma unroll
                    for (int kh = 0; kh < 3; ++kh)
#pragma unroll
                        for (int kw = 0; kw < 3; ++kw)
                            s += rows[i + kh][cc + kw] * wreg[kh * 3 + kw];
                    acc[i][cc] = s;
                }
        }
    }

    if (active) {
        float* op = out + (size_t)bid * 3136;
#pragma unroll
        for (int i = 0; i < 2; ++i)
#pragma unroll
            for (int cc = 0; cc < 7; ++cc)
                op[(r0 + i) * 56 + (c0 + cc)] = acc[i][cc];
    }
}

extern "C" void kernel_launch(void* const* d_in, const int* in_sizes, int n_in,
                              void* d_out, int out_size, void* d_ws, size_t ws_size,
                              hipStream_t stream) {
    const float* x    = (const float*)d_in[0];
    const float* wv   = (const float*)d_in[1];
    const int*   widx = (const int*)d_in[2];
    float* out = (float*)d_out;
    (void)in_sizes; (void)n_in; (void)out_size; (void)d_ws; (void)ws_size;

    sparse_conv_kernel<<<dim3(32 * 256), dim3(BDIM), 0, stream>>>(x, wv, widx, out);
}

// Round 2
// 210.301 us; speedup vs baseline: 7.5012x; 7.5012x over previous
//
#include <hip/hip_runtime.h>
#include <hip/hip_bf16.h>

// Sparse conv2d as bf16 implicit GEMM (densified weights).
// x:[32,256,56,56]f32  w_vals:[256,64,3,3]f32  w_idx:[256,64]i32  out:[32,256,56,56]f32
//
// ws layout: Wd bf16 [9][256][256] (1,179,648 B) | Xp bf16 [32][58][58][256] (55,115,776 B)

typedef __attribute__((ext_vector_type(8))) short bf16x8;
typedef __attribute__((ext_vector_type(4))) float f32x4;

#define WD_BYTES 1179648
#define XP_BYTES 55115776
#define WS_NEED  (WD_BYTES + XP_BYTES)
#define NPIX     100352           // 32*56*56

// ---------------- preprocessing ----------------

__global__ __launch_bounds__(64) void scatter_w(
    const float* __restrict__ wv, const int* __restrict__ widx,
    __hip_bfloat16* __restrict__ wd)
{
    int o = blockIdx.x;          // 256
    int j = threadIdx.x;         // 64
    int cin = widx[o * 64 + j];
    const float* src = wv + (size_t)(o * 64 + j) * 9;
#pragma unroll
    for (int k = 0; k < 9; ++k)
        wd[(size_t)k * 65536 + o * 256 + cin] = __float2bfloat16(src[k]);
}

// One block per (b, h): transpose [256 c][56 w] fp32 -> bf16 NHWC padded.
__global__ __launch_bounds__(256) void x_to_nhwc(
    const float* __restrict__ x, __hip_bfloat16* __restrict__ xp)
{
    int blk = blockIdx.x;
    int b = blk / 56, h = blk - (blk / 56) * 56;
    __shared__ __hip_bfloat16 tile[56][264];   // padded row

    int c = threadIdx.x;
    const float* src = x + ((size_t)(b * 256 + c)) * 3136 + h * 56;
    float vals[56];
#pragma unroll
    for (int i = 0; i < 14; ++i) {
        float4 v = *reinterpret_cast<const float4*>(src + i * 4);
        vals[i * 4 + 0] = v.x; vals[i * 4 + 1] = v.y;
        vals[i * 4 + 2] = v.z; vals[i * 4 + 3] = v.w;
    }
#pragma unroll
    for (int w = 0; w < 56; ++w) tile[w][c] = __float2bfloat16(vals[w]);
    __syncthreads();

    // Xp[b][h+1][w+1][c], row stride 512 B, coalesced 16-B chunks.
    char* obase = (char*)xp + (((size_t)b * 58 + (h + 1)) * 58) * 512;
#pragma unroll
    for (int k = 0; k < 7; ++k) {
        int i = threadIdx.x + k * 256;
        int w = i >> 5, cc = i & 31;
        bf16x8 v = *reinterpret_cast<const bf16x8*>(&tile[w][cc * 8]);
        *reinterpret_cast<bf16x8*>(obase + (size_t)(w + 1) * 512 + cc * 16) = v;
    }
}

// ---------------- main GEMM ----------------

__device__ inline void gload_lds16(const void* g, void* l) {
    __builtin_amdgcn_global_load_lds(
        (const __attribute__((address_space(1))) void*)g,
        (__attribute__((address_space(3))) void*)l, 16, 0, 0);
}

__global__ __launch_bounds__(256) void sparse_conv_mfma(
    const __hip_bfloat16* __restrict__ wd, const __hip_bfloat16* __restrict__ xp,
    float* __restrict__ out)
{
    __shared__ char lds[16384];
    char* As = lds;              // [128 o][32 c] bf16, row = 64 B
    char* Bs = lds + 8192;       // [128 p][32 c] bf16

    int bid = blockIdx.x;
    int swz = (bid & 7) * 196 + (bid >> 3);   // XCD swizzle, 1568 = 8*196
    int mt = swz & 1;            // 2 M-tiles of 128 o
    int nt = swz >> 1;           // 784 N-tiles of 128 px

    int t = threadIdx.x;
    int lane = t & 63, wid = t >> 6;
    int wr = wid >> 1, wc = wid & 1;

    // staging: thread stages rows (t>>2) and (t>>2)+64, 16-B chunk (t&3)
    int srow = t >> 2, schunk = t & 3;
    int pA0 = nt * 128 + srow, pA1 = pA0 + 64;
    unsigned pb0 = (unsigned)pA0 / 3136u; int pr0 = pA0 - pb0 * 3136;
    unsigned ph0 = (unsigned)pr0 / 56u;   int pw0 = pr0 - ph0 * 56;
    unsigned pb1 = (unsigned)pA1 / 3136u; int pr1 = pA1 - pb1 * 3136;
    unsigned ph1 = (unsigned)pr1 / 56u;   int pw1 = pr1 - ph1 * 56;

    const char* wdB = (const char*)wd;
    const char* xpB = (const char*)xp;

    // wave-uniform LDS bases (HW adds lane*16)
    char* lA0 = As + wid * 1024;  char* lA1 = As + 4096 + wid * 1024;
    char* lB0 = Bs + wid * 1024;  char* lB1 = Bs + 4096 + wid * 1024;

    f32x4 acc[4][4] = {};

    for (int k9 = 0; k9 < 9; ++k9) {
        int kh = k9 / 3, kw = k9 - (k9 / 3) * 3;
        int aoff0 = k9 * 131072 + (mt * 128 + srow) * 512 + schunk * 16;
        int aoff1 = aoff0 + 64 * 512;
        int xoff0 = ((pb0 * 58 + ph0 + kh) * 58 + pw0 + kw) * 512 + schunk * 16;
        int xoff1 = ((pb1 * 58 + ph1 + kh) * 58 + pw1 + kw) * 512 + schunk * 16;

        for (int c0b = 0; c0b < 512; c0b += 64) {   // c0 bytes: 256 ch * 2B, step 32ch
            __syncthreads();                         // waves done with prev LDS
            gload_lds16(wdB + aoff0 + c0b, lA0);
            gload_lds16(wdB + aoff1 + c0b, lA1);
            gload_lds16(xpB + xoff0 + c0b, lB0);
            gload_lds16(xpB + xoff1 + c0b, lB1);
            __syncthreads();                         // compiler drains vmcnt(0)

            const char* aBase = As + (wr * 64 + (lane & 15)) * 64 + (lane >> 4) * 16;
            const char* bBase = Bs + (wc * 64 + (lane & 15)) * 64 + (lane >> 4) * 16;
            bf16x8 af[4], bf[4];
#pragma unroll
            for (int i = 0; i < 4; ++i) {
                af[i] = *reinterpret_cast<const bf16x8*>(aBase + i * 16 * 64);
                bf[i] = *reinterpret_cast<const bf16x8*>(bBase + i * 16 * 64);
            }
#pragma unroll
            for (int mi = 0; mi < 4; ++mi)
#pragma unroll
                for (int ni = 0; ni < 4; ++ni)
                    acc[mi][ni] = __builtin_amdgcn_mfma_f32_16x16x32_bf16(
                        af[mi], bf[ni], acc[mi][ni], 0, 0, 0);
        }
    }

    // epilogue: out[b][o][rem]
#pragma unroll
    for (int ni = 0; ni < 4; ++ni) {
        int p = nt * 128 + wc * 64 + ni * 16 + (lane & 15);
        unsigned pb = (unsigned)p / 3136u;
        int rem = p - pb * 3136;
#pragma unroll
        for (int mi = 0; mi < 4; ++mi) {
            int o = mt * 128 + wr * 64 + mi * 16 + (lane >> 4) * 4;
            float* dst = out + ((size_t)pb * 256 + o) * 3136 + rem;
#pragma unroll
            for (int r = 0; r < 4; ++r) dst[(size_t)r * 3136] = acc[mi][ni][r];
        }
    }
}

// ---------------- fallback direct kernel (ws too small) ----------------

#define BDIM 256
__global__ __launch_bounds__(BDIM) void sparse_conv_direct(
    const float* __restrict__ x, const float* __restrict__ wv,
    const int* __restrict__ widx, float* __restrict__ out)
{
    const int bid = blockIdx.x;
    const int b = bid >> 8, o = bid & 255;
    const int tid = threadIdx.x;
    __shared__ float plane[58 * 60];
    const int rt = tid >> 3, ct = tid & 7;
    const int r0 = rt * 2, c0 = ct * 7;
    const bool active = (rt < 28);
    float acc[2][7];
#pragma unroll
    for (int i = 0; i < 2; ++i)
#pragma unroll
        for (int c = 0; c < 7; ++c) acc[i][c] = 0.f;
    const float* xb = x + (size_t)b * 256 * 3136;
    const int* idxp = widx + o * 64;
    const float* wp0 = wv + (size_t)o * 64 * 9;
    for (int j = 0; j < 64; ++j) {
        const int cin = idxp[j];
        const float* src = xb + cin * 3136;
        __syncthreads();
        for (int i = tid; i < 58 * 58; i += BDIM) {
            const int r = i / 58, c = i - r * 58;
            const int h = r - 1, w = c - 1;
            float v = 0.f;
            if ((unsigned)h < 56u && (unsigned)w < 56u) v = src[h * 56 + w];
            plane[r * 60 + c] = v;
        }
        float wreg[9];
#pragma unroll
        for (int k = 0; k < 9; ++k) wreg[k] = wp0[j * 9 + k];
        __syncthreads();
        if (active) {
            float rows[4][9];
#pragma unroll
            for (int dr = 0; dr < 4; ++dr)
#pragma unroll
                for (int cc = 0; cc < 9; ++cc)
                    rows[dr][cc] = plane[(r0 + dr) * 60 + (c0 + cc)];
#pragma unroll
            for (int i = 0; i < 2; ++i)
#pragma unroll
                for (int cc = 0; cc < 7; ++cc) {
                    float s = acc[i][cc];
#pragma unroll
                    for (int kh = 0; kh < 3; ++kh)
#pragma unroll
                        for (int kw = 0; kw < 3; ++kw)
                            s += rows[i + kh][cc + kw] * wreg[kh * 3 + kw];
                    acc[i][cc] = s;
                }
        }
    }
    if (active) {
        float* op = out + (size_t)bid * 3136;
#pragma unroll
        for (int i = 0; i < 2; ++i)
#pragma unroll
            for (int cc = 0; cc < 7; ++cc)
                op[(r0 + i) * 56 + (c0 + cc)] = acc[i][cc];
    }
}

extern "C" void kernel_launch(void* const* d_in, const int* in_sizes, int n_in,
                              void* d_out, int out_size, void* d_ws, size_t ws_size,
                              hipStream_t stream) {
    const float* x    = (const float*)d_in[0];
    const float* wv   = (const float*)d_in[1];
    const int*   widx = (const int*)d_in[2];
    float* out = (float*)d_out;
    (void)in_sizes; (void)n_in; (void)out_size;

    if (ws_size < (size_t)WS_NEED) {
        sparse_conv_direct<<<dim3(32 * 256), dim3(BDIM), 0, stream>>>(x, wv, widx, out);
        return;
    }

    __hip_bfloat16* wd = (__hip_bfloat16*)d_ws;
    __hip_bfloat16* xp = (__hip_bfloat16*)((char*)d_ws + WD_BYTES);

    hipMemsetAsync(d_ws, 0, WS_NEED, stream);
    scatter_w<<<dim3(256), dim3(64), 0, stream>>>(wv, widx, wd);
    x_to_nhwc<<<dim3(32 * 56), dim3(256), 0, stream>>>(x, xp);
    sparse_conv_mfma<<<dim3(1568), dim3(256), 0, stream>>>(wd, xp, out);
}

// Round 3
// 177.170 us; speedup vs baseline: 8.9039x; 1.1870x over previous
//
#include <hip/hip_runtime.h>
#include <hip/hip_bf16.h>

// Sparse conv2d as bf16 implicit GEMM, 256x256x64 8-phase pipelined schedule.
// x:[32,256,56,56]f32  w_vals:[256,64,3,3]f32  w_idx:[256,64]i32  out:[32,256,56,56]f32
// ws: Wd bf16 [9][256 o][256 c] (1,179,648 B) | Xp bf16 [32][58][58][256] (55,115,776 B)

typedef __attribute__((ext_vector_type(8))) short bf16x8;
typedef __attribute__((ext_vector_type(4))) float f32x4;

#define WD_BYTES 1179648
#define XP_BYTES 55115776
#define WS_NEED  (WD_BYTES + XP_BYTES)

// ---------------- preprocessing ----------------

__global__ __launch_bounds__(64) void scatter_w(
    const float* __restrict__ wv, const int* __restrict__ widx,
    __hip_bfloat16* __restrict__ wd)
{
    int o = blockIdx.x, j = threadIdx.x;
    int cin = widx[o * 64 + j];
    const float* src = wv + (size_t)(o * 64 + j) * 9;
#pragma unroll
    for (int k = 0; k < 9; ++k)
        wd[(size_t)k * 65536 + o * 256 + cin] = __float2bfloat16(src[k]);
}

__global__ __launch_bounds__(256) void x_to_nhwc(
    const float* __restrict__ x, __hip_bfloat16* __restrict__ xp)
{
    int blk = blockIdx.x;
    int b = blk / 56, h = blk - (blk / 56) * 56;
    __shared__ __hip_bfloat16 tile[56][264];
    int c = threadIdx.x;
    const float* src = x + ((size_t)(b * 256 + c)) * 3136 + h * 56;
    float vals[56];
#pragma unroll
    for (int i = 0; i < 14; ++i) {
        float4 v = *reinterpret_cast<const float4*>(src + i * 4);
        vals[i*4+0] = v.x; vals[i*4+1] = v.y; vals[i*4+2] = v.z; vals[i*4+3] = v.w;
    }
#pragma unroll
    for (int w = 0; w < 56; ++w) tile[w][c] = __float2bfloat16(vals[w]);
    __syncthreads();
    char* obase = (char*)xp + (((size_t)b * 58 + (h + 1)) * 58) * 512;
#pragma unroll
    for (int k = 0; k < 7; ++k) {
        int i = threadIdx.x + k * 256;
        int w = i >> 5, cc = i & 31;
        bf16x8 v = *reinterpret_cast<const bf16x8*>(&tile[w][cc * 8]);
        *reinterpret_cast<bf16x8*>(obase + (size_t)(w + 1) * 512 + cc * 16) = v;
    }
}

// Zero the halo borders of Xp (rows h=0,57; cols w=0,57).
__global__ __launch_bounds__(64) void zero_borders(__hip_bfloat16* __restrict__ xp)
{
    int i = blockIdx.x;            // 32 * 228
    int b = i / 228, r = i - b * 228;
    int h, w;
    if (r < 58)       { h = 0;  w = r; }
    else if (r < 116) { h = 57; w = r - 58; }
    else if (r < 172) { h = r - 116 + 1; w = 0; }
    else              { h = r - 172 + 1; w = 57; }
    char* dst = (char*)xp + (((size_t)b * 58 + h) * 58 + w) * 512 + threadIdx.x * 8;
    *reinterpret_cast<float2*>(dst) = float2{0.f, 0.f};
}

// ---------------- 8-phase GEMM ----------------

__device__ __forceinline__ void gload_lds16(const void* g, void* l) {
    __builtin_amdgcn_global_load_lds(
        (const __attribute__((address_space(1))) void*)g,
        (__attribute__((address_space(3))) void*)l, 16, 0, 0);
}

// A-half h of buffer BB, instruction J. Rows {h*64.., 128+h*64..} (wave-split halves).
template<int BB, int H, int J>
__device__ __forceinline__ void stage_a(const char* wdB, char* smem, int wid,
                                        int sa_off, int aoff) {
    gload_lds16(wdB + aoff + (H * 64 + J * 128) * 512 + sa_off,
                smem + BB * 65536 + (H * 64 + J * 128 + wid * 8) * 128);
}

// B-half h (pixel rows with bit5==h), instruction J.
template<int BB, int H, int J>
__device__ __forceinline__ void stage_b(const char* xpB, char* smem, int wid,
                                        int pbase, int axor, int boff) {
    int prb = (J * 2 + (wid >> 2)) * 64 + H * 32 + (wid & 3) * 8;  // wave-uniform
    gload_lds16(xpB + pbase + boff + axor,
                smem + BB * 65536 + 32768 + prb * 128);
}

template<int BB, int M>
__device__ __forceinline__ void load_a(const char* smem, int wr, int a_rb,
                                       int xq0, int xq1, bf16x8 (&af)[4][2]) {
#pragma unroll
    for (int mi = 0; mi < 4; ++mi) {
        int base = BB * 65536 + (wr * 128 + M * 64 + mi * 16) * 128 + a_rb;
        af[mi][0] = *(const bf16x8*)(smem + base + xq0);
        af[mi][1] = *(const bf16x8*)(smem + base + xq1);
    }
}

template<int BB, int N>
__device__ __forceinline__ void load_b(const char* smem, int wc, int a_rb,
                                       int xq0, int xq1, bf16x8 (&bfr)[2][2]) {
#pragma unroll
    for (int ni = 0; ni < 2; ++ni) {
        int base = BB * 65536 + 32768 + (wc * 64 + N * 32 + ni * 16) * 128 + a_rb;
        bfr[ni][0] = *(const bf16x8*)(smem + base + xq0);
        bfr[ni][1] = *(const bf16x8*)(smem + base + xq1);
    }
}

template<int M, int N>
__device__ __forceinline__ void mfma_q(bf16x8 (&af)[4][2], bf16x8 (&bfr)[2][2],
                                       f32x4 (&acc)[8][4]) {
    __builtin_amdgcn_s_setprio(1);
#pragma unroll
    for (int mi = 0; mi < 4; ++mi)
#pragma unroll
        for (int ni = 0; ni < 2; ++ni)
#pragma unroll
            for (int s = 0; s < 2; ++s)
                acc[M*4+mi][N*2+ni] = __builtin_amdgcn_mfma_f32_16x16x32_bf16(
                    af[mi][s], bfr[ni][s], acc[M*4+mi][N*2+ni], 0, 0, 0);
    __builtin_amdgcn_s_setprio(0);
}

__device__ __forceinline__ int pixoff(int p) {   // byte offset of pixel p in Xp (no kh/kw)
    int b = p / 3136; int r = p - b * 3136;
    int h = r / 56;   int w = r - h * 56;
    return ((b * 58 + h) * 58 + w) * 512;
}

__device__ __forceinline__ int aoff_t(int t) {   // A byte offset for K-tile t
    return (t >> 2) * 131072 + (t & 3) * 128;
}
__device__ __forceinline__ int boff_t(int t) {   // B byte offset (kh,kw + c-slice)
    int k9 = t >> 2; int kh = k9 / 3; int kw = k9 - 3 * kh;
    return (kh * 58 + kw) * 512 + (t & 3) * 128;
}

#define BAR() __builtin_amdgcn_s_barrier()
#define VMCNT4() asm volatile("s_waitcnt vmcnt(4)" ::: "memory")

__global__ __launch_bounds__(512, 2) void sparse_conv_mfma256(
    const __hip_bfloat16* __restrict__ wd, const __hip_bfloat16* __restrict__ xp,
    float* __restrict__ out)
{
    extern __shared__ char smem[];
    const char* wdB = (const char*)wd;
    const char* xpB = (const char*)xp;

    const int nt = blockIdx.x;            // 392 N-tiles of 256 px
    const int t = threadIdx.x;
    const int lane = t & 63, wid = t >> 6;
    const int wr = wid >> 2, wc = wid & 3;   // 2M x 4N wave grid

    // staging per-thread constants
    const int axor = (((lane & 7) ^ (lane >> 3)) * 16);
    const int sa_off = (wid * 8 + (lane >> 3)) * 512 + axor;
    // per-thread staged pixel base offsets for the 4 (h,j) B-instructions
    const int prow_base = (wid & 3) * 8 + (lane >> 3);
    const int pb00 = pixoff(nt * 256 + ((wid >> 2)) * 64 + prow_base);
    const int pb01 = pixoff(nt * 256 + (2 + (wid >> 2)) * 64 + prow_base);
    const int pb10 = pixoff(nt * 256 + ((wid >> 2)) * 64 + 32 + prow_base);
    const int pb11 = pixoff(nt * 256 + (2 + (wid >> 2)) * 64 + 32 + prow_base);

    // fragment-read per-thread constants
    const int a_rb = (lane & 15) * 128;
    const int xq0 = (((lane >> 4)) ^ (lane & 7)) * 16;
    const int xq1 = ((4 + (lane >> 4)) ^ (lane & 7)) * 16;

    f32x4 acc[8][4] = {};
    bf16x8 af[4][2], bfr[2][2];

    // ---- prologue: buf0 <- tile 0 (full), buf1 <- tile1 A-h0, B-h1 ----
    {
        int a0 = aoff_t(0), b0 = boff_t(0), a1 = aoff_t(1), b1 = boff_t(1);
        stage_a<0,0,0>(wdB, smem, wid, sa_off, a0);
        stage_a<0,0,1>(wdB, smem, wid, sa_off, a0);
        stage_a<0,1,0>(wdB, smem, wid, sa_off, a0);
        stage_a<0,1,1>(wdB, smem, wid, sa_off, a0);
        stage_b<0,0,0>(xpB, smem, wid, pb00, axor, b0);
        stage_b<0,0,1>(xpB, smem, wid, pb01, axor, b0);
        stage_b<0,1,0>(xpB, smem, wid, pb10, axor, b0);
        stage_b<0,1,1>(xpB, smem, wid, pb11, axor, b0);
        stage_a<1,0,0>(wdB, smem, wid, sa_off, a1);
        stage_a<1,0,1>(wdB, smem, wid, sa_off, a1);
        stage_b<1,1,0>(xpB, smem, wid, pb10, axor, b1);
        stage_b<1,1,1>(xpB, smem, wid, pb11, axor, b1);
        VMCNT4();
        BAR();
    }

    // ---- main loop: 18 iterations x 2 K-tiles (36 total) ----
    for (int it = 0; it < 18; ++it) {
        int t1 = 2 * it + 1;
        int t2 = 2 * it + 2; if (t2 >= 36) t2 -= 36;   // wrapped tail staging (dead data)
        int t3 = 2 * it + 3; if (t3 >= 36) t3 -= 36;
        const int a1 = aoff_t(t1), b1 = boff_t(t1);
        const int a2 = aoff_t(t2), b2 = boff_t(t2);
        const int a3 = aoff_t(t3), b3 = boff_t(t3);

        // ph1: q(0,0) on buf0; stage buf1.A-h1 (t1)
        load_a<0,0>(smem, wr, a_rb, xq0, xq1, af);
        load_b<0,0>(smem, wc, a_rb, xq0, xq1, bfr);
        stage_a<1,1,0>(wdB, smem, wid, sa_off, a1);
        stage_a<1,1,1>(wdB, smem, wid, sa_off, a1);
        BAR();  mfma_q<0,0>(af, bfr, acc);  BAR();

        // ph2: q(0,1); stage buf1.B-h0 (t1)
        load_b<0,1>(smem, wc, a_rb, xq0, xq1, bfr);
        stage_b<1,0,0>(xpB, smem, wid, pb00, axor, b1);
        stage_b<1,0,1>(xpB, smem, wid, pb01, axor, b1);
        BAR();  mfma_q<0,1>(af, bfr, acc);  BAR();

        // ph3: q(1,1) (B-h1 persists); stage buf0.A-h0 (t2)
        load_a<0,1>(smem, wr, a_rb, xq0, xq1, af);
        stage_a<0,0,0>(wdB, smem, wid, sa_off, a2);
        stage_a<0,0,1>(wdB, smem, wid, sa_off, a2);
        BAR();  mfma_q<1,1>(af, bfr, acc);  BAR();

        // ph4: q(1,0); stage buf0.B-h1 (t2); vmcnt(4) -> buf1 complete
        load_b<0,0>(smem, wc, a_rb, xq0, xq1, bfr);
        stage_b<0,1,0>(xpB, smem, wid, pb10, axor, b2);
        stage_b<0,1,1>(xpB, smem, wid, pb11, axor, b2);
        BAR();  mfma_q<1,0>(af, bfr, acc);
        VMCNT4();  BAR();

        // ph5: q(0,0) on buf1; stage buf0.A-h1 (t2)
        load_a<1,0>(smem, wr, a_rb, xq0, xq1, af);
        load_b<1,0>(smem, wc, a_rb, xq0, xq1, bfr);
        stage_a<0,1,0>(wdB, smem, wid, sa_off, a2);
        stage_a<0,1,1>(wdB, smem, wid, sa_off, a2);
        BAR();  mfma_q<0,0>(af, bfr, acc);  BAR();

        // ph6: q(0,1); stage buf0.B-h0 (t2)
        load_b<1,1>(smem, wc, a_rb, xq0, xq1, bfr);
        stage_b<0,0,0>(xpB, smem, wid, pb00, axor, b2);
        stage_b<0,0,1>(xpB, smem, wid, pb01, axor, b2);
        BAR();  mfma_q<0,1>(af, bfr, acc);  BAR();

        // ph7: q(1,1); stage buf1.A-h0 (t3)
        load_a<1,1>(smem, wr, a_rb, xq0, xq1, af);
        stage_a<1,0,0>(wdB, smem, wid, sa_off, a3);
        stage_a<1,0,1>(wdB, smem, wid, sa_off, a3);
        BAR();  mfma_q<1,1>(af, bfr, acc);  BAR();

        // ph8: q(1,0); stage buf1.B-h1 (t3); vmcnt(4) -> buf0 complete
        load_b<1,0>(smem, wc, a_rb, xq0, xq1, bfr);
        stage_b<1,1,0>(xpB, smem, wid, pb10, axor, b3);
        stage_b<1,1,1>(xpB, smem, wid, pb11, axor, b3);
        BAR();  mfma_q<1,0>(af, bfr, acc);
        VMCNT4();  BAR();
    }

    // ---- epilogue ----
#pragma unroll
    for (int n = 0; n < 4; ++n) {
        int p0 = nt * 256 + wc * 64 + n * 16;      // wave-uniform; 3136 % 16 == 0
        int pb = p0 / 3136;
        int rem0 = p0 - pb * 3136;
#pragma unroll
        for (int m = 0; m < 8; ++m) {
            int o = wr * 128 + m * 16 + (lane >> 4) * 4;
            float* dst = out + ((size_t)(pb * 256 + o)) * 3136 + rem0 + (lane & 15);
#pragma unroll
            for (int r = 0; r < 4; ++r) dst[(size_t)r * 3136] = acc[m][n][r];
        }
    }
}

// ---------------- fallback (ws too small) ----------------

__global__ __launch_bounds__(256) void sparse_conv_direct(
    const float* __restrict__ x, const float* __restrict__ wv,
    const int* __restrict__ widx, float* __restrict__ out)
{
    const int bid = blockIdx.x;
    const int b = bid >> 8, o = bid & 255;
    const int tid = threadIdx.x;
    __shared__ float plane[58 * 60];
    const int rt = tid >> 3, ct = tid & 7;
    const int r0 = rt * 2, c0 = ct * 7;
    const bool active = (rt < 28);
    float acc[2][7];
#pragma unroll
    for (int i = 0; i < 2; ++i)
#pragma unroll
        for (int c = 0; c < 7; ++c) acc[i][c] = 0.f;
    const float* xb = x + (size_t)b * 256 * 3136;
    const int* idxp = widx + o * 64;
    const float* wp0 = wv + (size_t)o * 64 * 9;
    for (int j = 0; j < 64; ++j) {
        const int cin = idxp[j];
        const float* src = xb + cin * 3136;
        __syncthreads();
        for (int i = tid; i < 58 * 58; i += 256) {
            const int r = i / 58, c = i - r * 58;
            const int h = r - 1, w = c - 1;
            float v = 0.f;
            if ((unsigned)h < 56u && (unsigned)w < 56u) v = src[h * 56 + w];
            plane[r * 60 + c] = v;
        }
        float wreg[9];
#pragma unroll
        for (int k = 0; k < 9; ++k) wreg[k] = wp0[j * 9 + k];
        __syncthreads();
        if (active) {
            float rows[4][9];
#pragma unroll
            for (int dr = 0; dr < 4; ++dr)
#pragma unroll
                for (int cc = 0; cc < 9; ++cc)
                    rows[dr][cc] = plane[(r0 + dr) * 60 + (c0 + cc)];
#pragma unroll
            for (int i = 0; i < 2; ++i)
#pragma unroll
                for (int cc = 0; cc < 7; ++cc) {
                    float s = acc[i][cc];
#pragma unroll
                    for (int kh = 0; kh < 3; ++kh)
#pragma unroll
                        for (int kw = 0; kw < 3; ++kw)
                            s += rows[i + kh][cc + kw] * wreg[kh * 3 + kw];
                    acc[i][cc] = s;
                }
        }
    }
    if (active) {
        float* op = out + (size_t)bid * 3136;
#pragma unroll
        for (int i = 0; i < 2; ++i)
#pragma unroll
            for (int cc = 0; cc < 7; ++cc)
                op[(r0 + i) * 56 + (c0 + cc)] = acc[i][cc];
    }
}

extern "C" void kernel_launch(void* const* d_in, const int* in_sizes, int n_in,
                              void* d_out, int out_size, void* d_ws, size_t ws_size,
                              hipStream_t stream) {
    const float* x    = (const float*)d_in[0];
    const float* wv   = (const float*)d_in[1];
    const int*   widx = (const int*)d_in[2];
    float* out = (float*)d_out;
    (void)in_sizes; (void)n_in; (void)out_size;

    if (ws_size < (size_t)WS_NEED) {
        sparse_conv_direct<<<dim3(32 * 256), dim3(256), 0, stream>>>(x, wv, widx, out);
        return;
    }

    __hip_bfloat16* wd = (__hip_bfloat16*)d_ws;
    __hip_bfloat16* xp = (__hip_bfloat16*)((char*)d_ws + WD_BYTES);

    hipMemsetAsync(d_ws, 0, WD_BYTES, stream);                       // Wd only
    zero_borders<<<dim3(32 * 228), dim3(64), 0, stream>>>(xp);       // Xp halo
    scatter_w<<<dim3(256), dim3(64), 0, stream>>>(wv, widx, wd);
    x_to_nhwc<<<dim3(32 * 56), dim3(256), 0, stream>>>(x, xp);

    (void)hipFuncSetAttribute((const void*)sparse_conv_mfma256,
                              hipFuncAttributeMaxDynamicSharedMemorySize, 131072);
    sparse_conv_mfma256<<<dim3(392), dim3(512), 131072, stream>>>(wd, xp, out);
}

// Round 4
// 171.470 us; speedup vs baseline: 9.1999x; 1.0332x over previous
//
#include <hip/hip_runtime.h>
#include <hip/hip_bf16.h>

// Sparse conv2d as bf16 implicit GEMM, 256(M) x 224(N) x 64(K) 8-phase schedule.
// x:[32,256,56,56]f32  w_vals:[256,64,3,3]f32  w_idx:[256,64]i32  out:[32,256,56,56]f32
// ws: Wd bf16 [9][256 o][256 c] (1,179,648 B) | Xp bf16 [32][58][58][256] (55,115,776 B)
// Grid 448 tiles of 224 px (3136 = 14*224: tiles never cross b or h-group).

typedef __attribute__((ext_vector_type(8))) short bf16x8;
typedef __attribute__((ext_vector_type(4))) float f32x4;

#define WD_BYTES 1179648
#define XP_BYTES 55115776
#define WS_NEED  (WD_BYTES + XP_BYTES)

// ---------------- preprocessing ----------------

__global__ __launch_bounds__(64) void scatter_w(
    const float* __restrict__ wv, const int* __restrict__ widx,
    __hip_bfloat16* __restrict__ wd)
{
    int o = blockIdx.x, j = threadIdx.x;
    int cin = widx[o * 64 + j];
    const float* src = wv + (size_t)(o * 64 + j) * 9;
#pragma unroll
    for (int k = 0; k < 9; ++k)
        wd[(size_t)k * 65536 + o * 256 + cin] = __float2bfloat16(src[k]);
}

__global__ __launch_bounds__(256) void x_to_nhwc(
    const float* __restrict__ x, __hip_bfloat16* __restrict__ xp)
{
    int blk = blockIdx.x;
    int b = blk / 56, h = blk - (blk / 56) * 56;
    __shared__ __hip_bfloat16 tile[56][264];
    int c = threadIdx.x;
    const float* src = x + ((size_t)(b * 256 + c)) * 3136 + h * 56;
    float vals[56];
#pragma unroll
    for (int i = 0; i < 14; ++i) {
        float4 v = *reinterpret_cast<const float4*>(src + i * 4);
        vals[i*4+0] = v.x; vals[i*4+1] = v.y; vals[i*4+2] = v.z; vals[i*4+3] = v.w;
    }
#pragma unroll
    for (int w = 0; w < 56; ++w) tile[w][c] = __float2bfloat16(vals[w]);
    __syncthreads();
    char* obase = (char*)xp + (((size_t)b * 58 + (h + 1)) * 58) * 512;
#pragma unroll
    for (int k = 0; k < 7; ++k) {
        int i = threadIdx.x + k * 256;
        int w = i >> 5, cc = i & 31;
        bf16x8 v = *reinterpret_cast<const bf16x8*>(&tile[w][cc * 8]);
        *reinterpret_cast<bf16x8*>(obase + (size_t)(w + 1) * 512 + cc * 16) = v;
    }
}

__global__ __launch_bounds__(64) void zero_borders(__hip_bfloat16* __restrict__ xp)
{
    int i = blockIdx.x;            // 32 * 228
    int b = i / 228, r = i - b * 228;
    int h, w;
    if (r < 58)       { h = 0;  w = r; }
    else if (r < 116) { h = 57; w = r - 58; }
    else if (r < 172) { h = r - 116 + 1; w = 0; }
    else              { h = r - 172 + 1; w = 57; }
    char* dst = (char*)xp + (((size_t)b * 58 + h) * 58 + w) * 512 + threadIdx.x * 8;
    *reinterpret_cast<float2*>(dst) = float2{0.f, 0.f};
}

// ---------------- 8-phase GEMM ----------------

__device__ __forceinline__ void gload_lds16(const void* g, void* l) {
    __builtin_amdgcn_global_load_lds(
        (const __attribute__((address_space(1))) void*)g,
        (__attribute__((address_space(3))) void*)l, 16, 0, 0);
}

// A-tile [256 rows][128 B]; instr (H,J) covers rows H*64+J*128 + wid*8 + lane>>3.
template<int BB, int H, int J>
__device__ __forceinline__ void stage_a(const char* wdB, char* smem, int wid,
                                        int sa_off, int aoff) {
    gload_lds16(wdB + aoff + (H * 64 + J * 128) * 512 + sa_off,
                smem + BB * 65536 + (H * 64 + J * 128 + wid * 8) * 128);
}

// B-tile [224 rows][128 B]; instr J covers rows J*64 + wid*8 + lane>>3 (J=3: wid<4).
template<int BB, int J>
__device__ __forceinline__ void stage_b(const char* xpB, char* smem, int wid,
                                        int pbJ, int boff) {
    gload_lds16(xpB + pbJ + boff,
                smem + BB * 65536 + 32768 + (J * 64 + wid * 8) * 128);
}

// A fragments: quadrant QM (2 m-frags), rows wr*64 + QM*32 + mi*16 + (lane&15).
template<int BB, int QM>
__device__ __forceinline__ void load_a(const char* smem, int wr, int a_rb,
                                       int xq0, int xq1, bf16x8 (&af)[2][2]) {
#pragma unroll
    for (int mi = 0; mi < 2; ++mi) {
        int base = BB * 65536 + (wr * 64 + QM * 32 + mi * 16) * 128 + a_rb;
        af[mi][0] = *(const bf16x8*)(smem + base + xq0);
        af[mi][1] = *(const bf16x8*)(smem + base + xq1);
    }
}

// B fragments: quadrant QN (QN==0: 4 frags, QN==1: 3), rows wc*112 + QN*64 + ni*16.
template<int BB, int QN>
__device__ __forceinline__ void load_b(const char* smem, int wc, int a_rb,
                                       int xq0, int xq1, bf16x8 (&bfr)[4][2]) {
#pragma unroll
    for (int ni = 0; ni < (QN ? 3 : 4); ++ni) {
        int base = BB * 65536 + 32768 + (wc * 112 + QN * 64 + ni * 16) * 128 + a_rb;
        bfr[ni][0] = *(const bf16x8*)(smem + base + xq0);
        bfr[ni][1] = *(const bf16x8*)(smem + base + xq1);
    }
}

template<int QM, int QN>
__device__ __forceinline__ void mfma_q(bf16x8 (&af)[2][2], bf16x8 (&bfr)[4][2],
                                       f32x4 (&acc)[4][7]) {
    __builtin_amdgcn_s_setprio(1);
#pragma unroll
    for (int mi = 0; mi < 2; ++mi)
#pragma unroll
        for (int ni = 0; ni < (QN ? 3 : 4); ++ni)
#pragma unroll
            for (int s = 0; s < 2; ++s)
                acc[QM*2+mi][QN*4+ni] = __builtin_amdgcn_mfma_f32_16x16x32_bf16(
                    af[mi][s], bfr[ni][s], acc[QM*2+mi][QN*4+ni], 0, 0, 0);
    __builtin_amdgcn_s_setprio(0);
}

__device__ __forceinline__ int pixoff(int p) {   // byte offset of pixel p in Xp
    int b = p / 3136; int r = p - b * 3136;
    int h = r / 56;   int w = r - h * 56;
    return ((b * 58 + h + 1) * 58 + (w + 1)) * 512;
}

__device__ __forceinline__ int aoff_t(int t) {
    return (t >> 2) * 131072 + (t & 3) * 128;
}
__device__ __forceinline__ int boff_t(int t) {   // relative to padded pixoff: -1 row/col + kh/kw
    int k9 = t >> 2; int kh = k9 / 3; int kw = k9 - 3 * kh;
    return ((kh - 1) * 58 + (kw - 1)) * 512 + (t & 3) * 128;
}

#define BAR() __builtin_amdgcn_s_barrier()
#define VMCNT4() asm volatile("s_waitcnt vmcnt(4)" ::: "memory")

__global__ __launch_bounds__(512, 2) void sparse_conv_mfma224(
    const __hip_bfloat16* __restrict__ wd, const __hip_bfloat16* __restrict__ xp,
    float* __restrict__ out)
{
    extern __shared__ char smem[];
    const char* wdB = (const char*)wd;
    const char* xpB = (const char*)xp;

    const int nt = blockIdx.x;            // 448 N-tiles of 224 px
    const int t = threadIdx.x;
    const int lane = t & 63, wid = t >> 6;
    const int wr = wid >> 1, wc = wid & 1;   // 4M x 2N wave grid

    // staging constants
    const int axor = (((lane & 7) ^ (lane >> 3)) * 16);
    const int sa_off = (wid * 8 + (lane >> 3)) * 512 + axor;
    const int prow = wid * 8 + (lane >> 3);
    const int pb0 = pixoff(nt * 224 +   0 + prow) + axor;
    const int pb1 = pixoff(nt * 224 +  64 + prow) + axor;
    const int pb2 = pixoff(nt * 224 + 128 + prow) + axor;
    const int pb3 = (wid < 4) ? (pixoff(nt * 224 + 192 + prow) + axor) : 0;

    // fragment-read constants
    const int a_rb = (lane & 15) * 128;
    const int xq0 = (((lane >> 4)) ^ (lane & 7)) * 16;
    const int xq1 = ((4 + (lane >> 4)) ^ (lane & 7)) * 16;

    f32x4 acc[4][7] = {};
    bf16x8 af[2][2], bfr[4][2];

    // ---- prologue: buf0 <- tile 0 (A+B), buf1 <- tile 1 (A only) ----
    {
        int a0 = aoff_t(0), b0 = boff_t(0), a1 = aoff_t(1);
        stage_a<0,0,0>(wdB, smem, wid, sa_off, a0);
        stage_a<0,0,1>(wdB, smem, wid, sa_off, a0);
        stage_a<0,1,0>(wdB, smem, wid, sa_off, a0);
        stage_a<0,1,1>(wdB, smem, wid, sa_off, a0);
        stage_b<0,0>(xpB, smem, wid, pb0, b0);
        stage_b<0,1>(xpB, smem, wid, pb1, b0);
        stage_b<0,2>(xpB, smem, wid, pb2, b0);
        if (wid < 4) stage_b<0,3>(xpB, smem, wid, pb3, b0);
        stage_a<1,0,0>(wdB, smem, wid, sa_off, a1);
        stage_a<1,0,1>(wdB, smem, wid, sa_off, a1);
        stage_a<1,1,0>(wdB, smem, wid, sa_off, a1);
        stage_a<1,1,1>(wdB, smem, wid, sa_off, a1);
        VMCNT4();
        BAR();
    }

    // ---- main loop: 18 iterations x 2 K-tiles (36 total) ----
    for (int it = 0; it < 18; ++it) {
        int t1 = 2 * it + 1;                            // always < 36
        int t2 = 2 * it + 2; if (t2 >= 36) t2 -= 36;    // wrapped dead staging
        int t3 = 2 * it + 3; if (t3 >= 36) t3 -= 36;
        const int b1 = boff_t(t1);
        const int a2 = aoff_t(t2), b2 = boff_t(t2);
        const int a3 = aoff_t(t3);

        // ph1: q(qm0,qn0) on buf0; stage buf1.B J0,J1 (t1)
        load_a<0,0>(smem, wr, a_rb, xq0, xq1, af);
        load_b<0,0>(smem, wc, a_rb, xq0, xq1, bfr);
        stage_b<1,0>(xpB, smem, wid, pb0, b1);
        stage_b<1,1>(xpB, smem, wid, pb1, b1);
        BAR();  mfma_q<0,0>(af, bfr, acc);  BAR();

        // ph2: q(qm0,qn1); stage buf1.B J2,J3 (t1)
        load_b<0,1>(smem, wc, a_rb, xq0, xq1, bfr);
        stage_b<1,2>(xpB, smem, wid, pb2, b1);
        if (wid < 4) stage_b<1,3>(xpB, smem, wid, pb3, b1);
        BAR();  mfma_q<0,1>(af, bfr, acc);  BAR();

        // ph3: q(qm1,qn1) (B regs persist); no staging
        load_a<0,1>(smem, wr, a_rb, xq0, xq1, af);
        BAR();  mfma_q<1,1>(af, bfr, acc);  BAR();

        // ph4: q(qm1,qn0); stage buf0.A x4 (t2); vmcnt(4) -> buf1 (t1) complete
        load_b<0,0>(smem, wc, a_rb, xq0, xq1, bfr);
        stage_a<0,0,0>(wdB, smem, wid, sa_off, a2);
        stage_a<0,0,1>(wdB, smem, wid, sa_off, a2);
        stage_a<0,1,0>(wdB, smem, wid, sa_off, a2);
        stage_a<0,1,1>(wdB, smem, wid, sa_off, a2);
        BAR();  mfma_q<1,0>(af, bfr, acc);
        VMCNT4();  BAR();

        // ph5: q(qm0,qn0) on buf1; stage buf0.B J0,J1 (t2)
        load_a<1,0>(smem, wr, a_rb, xq0, xq1, af);
        load_b<1,0>(smem, wc, a_rb, xq0, xq1, bfr);
        stage_b<0,0>(xpB, smem, wid, pb0, b2);
        stage_b<0,1>(xpB, smem, wid, pb1, b2);
        BAR();  mfma_q<0,0>(af, bfr, acc);  BAR();

        // ph6: q(qm0,qn1); stage buf0.B J2,J3 (t2)
        load_b<1,1>(smem, wc, a_rb, xq0, xq1, bfr);
        stage_b<0,2>(xpB, smem, wid, pb2, b2);
        if (wid < 4) stage_b<0,3>(xpB, smem, wid, pb3, b2);
        BAR();  mfma_q<0,1>(af, bfr, acc);  BAR();

        // ph7: q(qm1,qn1); no staging
        load_a<1,1>(smem, wr, a_rb, xq0, xq1, af);
        BAR();  mfma_q<1,1>(af, bfr, acc);  BAR();

        // ph8: q(qm1,qn0); stage buf1.A x4 (t3); vmcnt(4) -> buf0 (t2) complete
        load_b<1,0>(smem, wc, a_rb, xq0, xq1, bfr);
        stage_a<1,0,0>(wdB, smem, wid, sa_off, a3);
        stage_a<1,0,1>(wdB, smem, wid, sa_off, a3);
        stage_a<1,1,0>(wdB, smem, wid, sa_off, a3);
        stage_a<1,1,1>(wdB, smem, wid, sa_off, a3);
        BAR();  mfma_q<1,0>(af, bfr, acc);
        VMCNT4();  BAR();
    }

    // ---- epilogue: out[b][o][px] ----
#pragma unroll
    for (int n = 0; n < 7; ++n) {
        int p0 = nt * 224 + wc * 112 + n * 16;   // wave-uniform; 16 | 3136
        int pb = p0 / 3136;
        int rem0 = p0 - pb * 3136;
#pragma unroll
        for (int m = 0; m < 4; ++m) {
            int o = wr * 64 + m * 16 + (lane >> 4) * 4;
            float* dst = out + ((size_t)(pb * 256 + o)) * 3136 + rem0 + (lane & 15);
#pragma unroll
            for (int r = 0; r < 4; ++r) dst[(size_t)r * 3136] = acc[m][n][r];
        }
    }
}

// ---------------- fallback (ws too small) ----------------

__global__ __launch_bounds__(256) void sparse_conv_direct(
    const float* __restrict__ x, const float* __restrict__ wv,
    const int* __restrict__ widx, float* __restrict__ out)
{
    const int bid = blockIdx.x;
    const int b = bid >> 8, o = bid & 255;
    const int tid = threadIdx.x;
    __shared__ float plane[58 * 60];
    const int rt = tid >> 3, ct = tid & 7;
    const int r0 = rt * 2, c0 = ct * 7;
    const bool active = (rt < 28);
    float acc[2][7];
#pragma unroll
    for (int i = 0; i < 2; ++i)
#pragma unroll
        for (int c = 0; c < 7; ++c) acc[i][c] = 0.f;
    const float* xb = x + (size_t)b * 256 * 3136;
    const int* idxp = widx + o * 64;
    const float* wp0 = wv + (size_t)o * 64 * 9;
    for (int j = 0; j < 64; ++j) {
        const int cin = idxp[j];
        const float* src = xb + cin * 3136;
        __syncthreads();
        for (int i = tid; i < 58 * 58; i += 256) {
            const int r = i / 58, c = i - r * 58;
            const int h = r - 1, w = c - 1;
            float v = 0.f;
            if ((unsigned)h < 56u && (unsigned)w < 56u) v = src[h * 56 + w];
            plane[r * 60 + c] = v;
        }
        float wreg[9];
#pragma unroll
        for (int k = 0; k < 9; ++k) wreg[k] = wp0[j * 9 + k];
        __syncthreads();
        if (active) {
            float rows[4][9];
#pragma unroll
            for (int dr = 0; dr < 4; ++dr)
#pragma unroll
                for (int cc = 0; cc < 9; ++cc)
                    rows[dr][cc] = plane[(r0 + dr) * 60 + (c0 + cc)];
#pragma unroll
            for (int i = 0; i < 2; ++i)
#pragma unroll
                for (int cc = 0; cc < 7; ++cc) {
                    float s = acc[i][cc];
#pragma unroll
                    for (int kh = 0; kh < 3; ++kh)
#pragma unroll
                        for (int kw = 0; kw < 3; ++kw)
                            s += rows[i + kh][cc + kw] * wreg[kh * 3 + kw];
                    acc[i][cc] = s;
                }
        }
    }
    if (active) {
        float* op = out + (size_t)bid * 3136;
#pragma unroll
        for (int i = 0; i < 2; ++i)
#pragma unroll
            for (int cc = 0; cc < 7; ++cc)
                op[(r0 + i) * 56 + (c0 + cc)] = acc[i][cc];
    }
}

extern "C" void kernel_launch(void* const* d_in, const int* in_sizes, int n_in,
                              void* d_out, int out_size, void* d_ws, size_t ws_size,
                              hipStream_t stream) {
    const float* x    = (const float*)d_in[0];
    const float* wv   = (const float*)d_in[1];
    const int*   widx = (const int*)d_in[2];
    float* out = (float*)d_out;
    (void)in_sizes; (void)n_in; (void)out_size;

    if (ws_size < (size_t)WS_NEED) {
        sparse_conv_direct<<<dim3(32 * 256), dim3(256), 0, stream>>>(x, wv, widx, out);
        return;
    }

    __hip_bfloat16* wd = (__hip_bfloat16*)d_ws;
    __hip_bfloat16* xp = (__hip_bfloat16*)((char*)d_ws + WD_BYTES);

    hipMemsetAsync(d_ws, 0, WD_BYTES, stream);                       // Wd only
    zero_borders<<<dim3(32 * 228), dim3(64), 0, stream>>>(xp);       // Xp halo
    scatter_w<<<dim3(256), dim3(64), 0, stream>>>(wv, widx, wd);
    x_to_nhwc<<<dim3(32 * 56), dim3(256), 0, stream>>>(x, xp);

    (void)hipFuncSetAttribute((const void*)sparse_conv_mfma224,
                              hipFuncAttributeMaxDynamicSharedMemorySize, 131072);
    sparse_conv_mfma224<<<dim3(448), dim3(512), 131072, stream>>>(wd, xp, out);
}

// Round 5
// 157.600 us; speedup vs baseline: 10.0096x; 1.0880x over previous
//
#include <hip/hip_runtime.h>
#include <hip/hip_bf16.h>

// Sparse conv2d as bf16 implicit GEMM, 256(M) x 224(N) x 64(K), 2-phase/K-tile
// schedule with full operand persistence (A + both B-halves in registers).
// x:[32,256,56,56]f32  w_vals:[256,64,3,3]f32  w_idx:[256,64]i32  out:[32,256,56,56]f32
// ws: Wd bf16 [9][256 o][256 c] (1,179,648 B) | Xp bf16 [32][58][58][256] (55,115,776 B)
// Grid 448 tiles of 224 px (3136 = 14*224: tiles never cross b or h-group).

typedef __attribute__((ext_vector_type(8))) short bf16x8;
typedef __attribute__((ext_vector_type(4))) float f32x4;

#define WD_BYTES 1179648
#define XP_BYTES 55115776
#define WS_NEED  (WD_BYTES + XP_BYTES)

// ---------------- preprocessing ----------------

// Block o: zero Wd[:, o, :] (only writer of row o), then scatter its 64 taps.
__global__ __launch_bounds__(64) void scatter_w(
    const float* __restrict__ wv, const int* __restrict__ widx,
    __hip_bfloat16* __restrict__ wd)
{
    int o = blockIdx.x, j = threadIdx.x;
#pragma unroll
    for (int k = 0; k < 9; ++k)
        reinterpret_cast<float2*>(wd + (size_t)k * 65536 + o * 256)[j] = float2{0.f, 0.f};
    __syncthreads();
    int cin = widx[o * 64 + j];
    const float* src = wv + (size_t)(o * 64 + j) * 9;
#pragma unroll
    for (int k = 0; k < 9; ++k)
        wd[(size_t)k * 65536 + o * 256 + cin] = __float2bfloat16(src[k]);
}

// Block (b,h): transpose [256 c][56 w] fp32 -> bf16 NHWC padded row h+1,
// plus halo borders (w=0,57 of this row; full rows 0/57 when h==0/55).
__global__ __launch_bounds__(256) void x_to_nhwc(
    const float* __restrict__ x, __hip_bfloat16* __restrict__ xp)
{
    int blk = blockIdx.x;
    int b = blk / 56, h = blk - (blk / 56) * 56;
    __shared__ __hip_bfloat16 tile[56][264];
    int c = threadIdx.x;
    const float* src = x + ((size_t)(b * 256 + c)) * 3136 + h * 56;
    float vals[56];
#pragma unroll
    for (int i = 0; i < 14; ++i) {
        float4 v = *reinterpret_cast<const float4*>(src + i * 4);
        vals[i*4+0] = v.x; vals[i*4+1] = v.y; vals[i*4+2] = v.z; vals[i*4+3] = v.w;
    }
#pragma unroll
    for (int w = 0; w < 56; ++w) tile[w][c] = __float2bfloat16(vals[w]);

    // halo borders (independent of tile[]): row h+1, pixels w=0 and w=57
    char* rowb = (char*)xp + (((size_t)b * 58 + (h + 1)) * 58) * 512;
    int tid = threadIdx.x;
    if (tid < 64)        reinterpret_cast<double*>(rowb)[tid] = 0.0;
    else if (tid < 128)  *reinterpret_cast<double*>(rowb + 57 * 512 + (tid - 64) * 8) = 0.0;
    if (h == 0) {
        char* r0 = (char*)xp + (((size_t)b * 58 + 0) * 58) * 512;
        for (int i = tid; i < 58 * 64; i += 256) reinterpret_cast<double*>(r0)[i] = 0.0;
    }
    if (h == 55) {
        char* r57 = (char*)xp + (((size_t)b * 58 + 57) * 58) * 512;
        for (int i = tid; i < 58 * 64; i += 256) reinterpret_cast<double*>(r57)[i] = 0.0;
    }

    __syncthreads();
    char* obase = (char*)xp + (((size_t)b * 58 + (h + 1)) * 58) * 512;
#pragma unroll
    for (int k = 0; k < 7; ++k) {
        int i = threadIdx.x + k * 256;
        int w = i >> 5, cc = i & 31;
        bf16x8 v = *reinterpret_cast<const bf16x8*>(&tile[w][cc * 8]);
        *reinterpret_cast<bf16x8*>(obase + (size_t)(w + 1) * 512 + cc * 16) = v;
    }
}

// ---------------- 2-phase/K-tile GEMM ----------------

__device__ __forceinline__ void gload_lds16(const void* g, void* l) {
    __builtin_amdgcn_global_load_lds(
        (const __attribute__((address_space(1))) void*)g,
        (__attribute__((address_space(3))) void*)l, 16, 0, 0);
}

// A-tile [256 rows][128 B]; instr (H,J) covers rows H*64+J*128 + wid*8 + lane>>3.
template<int BB, int H, int J>
__device__ __forceinline__ void stage_a(const char* wdB, char* smem, int wid,
                                        int sa_off, int aoff) {
    gload_lds16(wdB + aoff + (H * 64 + J * 128) * 512 + sa_off,
                smem + BB * 65536 + (H * 64 + J * 128 + wid * 8) * 128);
}

// B-tile [224 rows][128 B]; instr J covers rows J*64 + wid*8 + lane>>3 (J=3: wid<4).
template<int BB, int J>
__device__ __forceinline__ void stage_b(const char* xpB, char* smem, int wid,
                                        int pbJ, int boff) {
    gload_lds16(xpB + pbJ + boff,
                smem + BB * 65536 + 32768 + (J * 64 + wid * 8) * 128);
}

// All 4 A m-frags: rows wr*64 + mi*16 + (lane&15).
template<int BB>
__device__ __forceinline__ void load_a(const char* smem, int wr, int a_rb,
                                       int xq0, int xq1, bf16x8 (&af)[4][2]) {
#pragma unroll
    for (int mi = 0; mi < 4; ++mi) {
        int base = BB * 65536 + (wr * 64 + mi * 16) * 128 + a_rb;
        af[mi][0] = *(const bf16x8*)(smem + base + xq0);
        af[mi][1] = *(const bf16x8*)(smem + base + xq1);
    }
}

// B half QN (QN==0: 4 frags, QN==1: 3), rows wc*112 + QN*64 + ni*16.
template<int BB, int QN, int NF>
__device__ __forceinline__ void load_b(const char* smem, int wc, int a_rb,
                                       int xq0, int xq1, bf16x8 (&bfr)[NF][2]) {
#pragma unroll
    for (int ni = 0; ni < (QN ? 3 : 4); ++ni) {
        int base = BB * 65536 + 32768 + (wc * 112 + QN * 64 + ni * 16) * 128 + a_rb;
        bfr[ni][0] = *(const bf16x8*)(smem + base + xq0);
        bfr[ni][1] = *(const bf16x8*)(smem + base + xq1);
    }
}

template<int QN, int NF>
__device__ __forceinline__ void mfma_half(bf16x8 (&af)[4][2], bf16x8 (&bfr)[NF][2],
                                          f32x4 (&acc)[4][7]) {
    __builtin_amdgcn_s_setprio(1);
#pragma unroll
    for (int mi = 0; mi < 4; ++mi)
#pragma unroll
        for (int ni = 0; ni < (QN ? 3 : 4); ++ni)
#pragma unroll
            for (int s = 0; s < 2; ++s)
                acc[mi][QN*4+ni] = __builtin_amdgcn_mfma_f32_16x16x32_bf16(
                    af[mi][s], bfr[ni][s], acc[mi][QN*4+ni], 0, 0, 0);
    __builtin_amdgcn_s_setprio(0);
}

__device__ __forceinline__ int pixoff(int p) {   // byte offset of pixel p in Xp
    int b = p / 3136; int r = p - b * 3136;
    int h = r / 56;   int w = r - h * 56;
    return ((b * 58 + h + 1) * 58 + (w + 1)) * 512;
}

__device__ __forceinline__ int aoff_t(int t) {
    return (t >> 2) * 131072 + (t & 3) * 128;
}
__device__ __forceinline__ int boff_t(int t) {   // relative to padded pixoff
    int k9 = t >> 2; int kh = k9 / 3; int kw = k9 - 3 * kh;
    return ((kh - 1) * 58 + (kw - 1)) * 512 + (t & 3) * 128;
}

#define BAR() __builtin_amdgcn_s_barrier()
#define VMCNT4() asm volatile("s_waitcnt vmcnt(4)" ::: "memory")

__global__ __launch_bounds__(512, 2) void sparse_conv_mfma224(
    const __hip_bfloat16* __restrict__ wd, const __hip_bfloat16* __restrict__ xp,
    float* __restrict__ out)
{
    extern __shared__ char smem[];
    const char* wdB = (const char*)wd;
    const char* xpB = (const char*)xp;

    const int nt = blockIdx.x;            // 448 N-tiles of 224 px
    const int t = threadIdx.x;
    const int lane = t & 63, wid = t >> 6;
    const int wr = wid >> 1, wc = wid & 1;   // 4M x 2N wave grid

    // staging constants
    const int axor = (((lane & 7) ^ (lane >> 3)) * 16);
    const int sa_off = (wid * 8 + (lane >> 3)) * 512 + axor;
    const int prow = wid * 8 + (lane >> 3);
    const int pb0 = pixoff(nt * 224 +   0 + prow) + axor;
    const int pb1 = pixoff(nt * 224 +  64 + prow) + axor;
    const int pb2 = pixoff(nt * 224 + 128 + prow) + axor;
    const int pb3 = (wid < 4) ? (pixoff(nt * 224 + 192 + prow) + axor) : 0;

    // fragment-read constants
    const int a_rb = (lane & 15) * 128;
    const int xq0 = (((lane >> 4)) ^ (lane & 7)) * 16;
    const int xq1 = ((4 + (lane >> 4)) ^ (lane & 7)) * 16;

    f32x4 acc[4][7] = {};
    bf16x8 af[4][2], bfr0[4][2], bfr1[3][2];

    // ---- prologue: buf0 <- tile 0 (A+B), buf1 <- tile 1 (A only) ----
    {
        int a0 = aoff_t(0), b0 = boff_t(0), a1 = aoff_t(1);
        stage_a<0,0,0>(wdB, smem, wid, sa_off, a0);
        stage_a<0,0,1>(wdB, smem, wid, sa_off, a0);
        stage_a<0,1,0>(wdB, smem, wid, sa_off, a0);
        stage_a<0,1,1>(wdB, smem, wid, sa_off, a0);
        stage_b<0,0>(xpB, smem, wid, pb0, b0);
        stage_b<0,1>(xpB, smem, wid, pb1, b0);
        stage_b<0,2>(xpB, smem, wid, pb2, b0);
        if (wid < 4) stage_b<0,3>(xpB, smem, wid, pb3, b0);
        stage_a<1,0,0>(wdB, smem, wid, sa_off, a1);
        stage_a<1,0,1>(wdB, smem, wid, sa_off, a1);
        stage_a<1,1,0>(wdB, smem, wid, sa_off, a1);
        stage_a<1,1,1>(wdB, smem, wid, sa_off, a1);
        VMCNT4();
        BAR();
    }

    // ---- main loop: 18 iterations x 2 K-tiles (36 total) ----
    // Per-wave vmcnt ledger (J3-wave / non-J3-wave):
    //  enter P1: outstanding 4 (buf1.A)
    //  P1 +B(t1) 4/3 -> 8/7 ; P2 +A(t2) 4 -> 12/11, VMCNT(4): drains buf1.A+B ✓
    //  P3 +B(t2) 4/3 -> 8/7 ; P4 +A(t3) 4 -> 12/11, VMCNT(4): drains buf0.A+B ✓
    for (int it = 0; it < 18; ++it) {
        int t1 = 2 * it + 1;                            // < 36
        int t2 = 2 * it + 2; if (t2 >= 36) t2 -= 36;    // wrapped dead staging
        int t3 = 2 * it + 3; if (t3 >= 36) t3 -= 36;
        const int b1 = boff_t(t1);
        const int a2 = aoff_t(t2), b2 = boff_t(t2);
        const int a3 = aoff_t(t3);

        // P1: buf0 A(8 rds) + B-h0(8 rds); stage buf1.B (t1); 32 MFMA
        load_a<0>(smem, wr, a_rb, xq0, xq1, af);
        load_b<0,0>(smem, wc, a_rb, xq0, xq1, bfr0);
        stage_b<1,0>(xpB, smem, wid, pb0, b1);
        stage_b<1,1>(xpB, smem, wid, pb1, b1);
        stage_b<1,2>(xpB, smem, wid, pb2, b1);
        if (wid < 4) stage_b<1,3>(xpB, smem, wid, pb3, b1);
        BAR();  mfma_half<0>(af, bfr0, acc);  BAR();

        // P2: buf0 B-h1(6 rds); stage buf0.A (t2); 24 MFMA; vmcnt -> buf1 ready
        load_b<0,1>(smem, wc, a_rb, xq0, xq1, bfr1);
        stage_a<0,0,0>(wdB, smem, wid, sa_off, a2);
        stage_a<0,0,1>(wdB, smem, wid, sa_off, a2);
        stage_a<0,1,0>(wdB, smem, wid, sa_off, a2);
        stage_a<0,1,1>(wdB, smem, wid, sa_off, a2);
        BAR();  mfma_half<1>(af, bfr1, acc);
        VMCNT4();  BAR();

        // P3: buf1 A + B-h0; stage buf0.B (t2); 32 MFMA
        load_a<1>(smem, wr, a_rb, xq0, xq1, af);
        load_b<1,0>(smem, wc, a_rb, xq0, xq1, bfr0);
        stage_b<0,0>(xpB, smem, wid, pb0, b2);
        stage_b<0,1>(xpB, smem, wid, pb1, b2);
        stage_b<0,2>(xpB, smem, wid, pb2, b2);
        if (wid < 4) stage_b<0,3>(xpB, smem, wid, pb3, b2);
        BAR();  mfma_half<0>(af, bfr0, acc);  BAR();

        // P4: buf1 B-h1; stage buf1.A (t3); 24 MFMA; vmcnt -> buf0 ready
        load_b<1,1>(smem, wc, a_rb, xq0, xq1, bfr1);
        stage_a<1,0,0>(wdB, smem, wid, sa_off, a3);
        stage_a<1,0,1>(wdB, smem, wid, sa_off, a3);
        stage_a<1,1,0>(wdB, smem, wid, sa_off, a3);
        stage_a<1,1,1>(wdB, smem, wid, sa_off, a3);
        BAR();  mfma_half<1>(af, bfr1, acc);
        VMCNT4();  BAR();
    }

    // ---- epilogue: out[b][o][px] ----
#pragma unroll
    for (int n = 0; n < 7; ++n) {
        int p0 = nt * 224 + wc * 112 + n * 16;   // wave-uniform; 16 | 3136
        int pb = p0 / 3136;
        int rem0 = p0 - pb * 3136;
#pragma unroll
        for (int m = 0; m < 4; ++m) {
            int o = wr * 64 + m * 16 + (lane >> 4) * 4;
            float* dst = out + ((size_t)(pb * 256 + o)) * 3136 + rem0 + (lane & 15);
#pragma unroll
            for (int r = 0; r < 4; ++r) dst[(size_t)r * 3136] = acc[m][n][r];
        }
    }
}

// ---------------- fallback (ws too small) ----------------

__global__ __launch_bounds__(256) void sparse_conv_direct(
    const float* __restrict__ x, const float* __restrict__ wv,
    const int* __restrict__ widx, float* __restrict__ out)
{
    const int bid = blockIdx.x;
    const int b = bid >> 8, o = bid & 255;
    const int tid = threadIdx.x;
    __shared__ float plane[58 * 60];
    const int rt = tid >> 3, ct = tid & 7;
    const int r0 = rt * 2, c0 = ct * 7;
    const bool active = (rt < 28);
    float acc[2][7];
#pragma unroll
    for (int i = 0; i < 2; ++i)
#pragma unroll
        for (int c = 0; c < 7; ++c) acc[i][c] = 0.f;
    const float* xb = x + (size_t)b * 256 * 3136;
    const int* idxp = widx + o * 64;
    const float* wp0 = wv + (size_t)o * 64 * 9;
    for (int j = 0; j < 64; ++j) {
        const int cin = idxp[j];
        const float* src = xb + cin * 3136;
        __syncthreads();
        for (int i = tid; i < 58 * 58; i += 256) {
            const int r = i / 58, c = i - r * 58;
            const int h = r - 1, w = c - 1;
            float v = 0.f;
            if ((unsigned)h < 56u && (unsigned)w < 56u) v = src[h * 56 + w];
            plane[r * 60 + c] = v;
        }
        float wreg[9];
#pragma unroll
        for (int k = 0; k < 9; ++k) wreg[k] = wp0[j * 9 + k];
        __syncthreads();
        if (active) {
            float rows[4][9];
#pragma unroll
            for (int dr = 0; dr < 4; ++dr)
#pragma unroll
                for (int cc = 0; cc < 9; ++cc)
                    rows[dr][cc] = plane[(r0 + dr) * 60 + (c0 + cc)];
#pragma unroll
            for (int i = 0; i < 2; ++i)
#pragma unroll
                for (int cc = 0; cc < 7; ++cc) {
                    float s = acc[i][cc];
#pragma unroll
                    for (int kh = 0; kh < 3; ++kh)
#pragma unroll
                        for (int kw = 0; kw < 3; ++kw)
                            s += rows[i + kh][cc + kw] * wreg[kh * 3 + kw];
                    acc[i][cc] = s;
                }
        }
    }
    if (active) {
        float* op = out + (size_t)bid * 3136;
#pragma unroll
        for (int i = 0; i < 2; ++i)
#pragma unroll
            for (int cc = 0; cc < 7; ++cc)
                op[(r0 + i) * 56 + (c0 + cc)] = acc[i][cc];
    }
}

extern "C" void kernel_launch(void* const* d_in, const int* in_sizes, int n_in,
                              void* d_out, int out_size, void* d_ws, size_t ws_size,
                              hipStream_t stream) {
    const float* x    = (const float*)d_in[0];
    const float* wv   = (const float*)d_in[1];
    const int*   widx = (const int*)d_in[2];
    float* out = (float*)d_out;
    (void)in_sizes; (void)n_in; (void)out_size;

    if (ws_size < (size_t)WS_NEED) {
        sparse_conv_direct<<<dim3(32 * 256), dim3(256), 0, stream>>>(x, wv, widx, out);
        return;
    }

    __hip_bfloat16* wd = (__hip_bfloat16*)d_ws;
    __hip_bfloat16* xp = (__hip_bfloat16*)((char*)d_ws + WD_BYTES);

    scatter_w<<<dim3(256), dim3(64), 0, stream>>>(wv, widx, wd);
    x_to_nhwc<<<dim3(32 * 56), dim3(256), 0, stream>>>(x, xp);

    (void)hipFuncSetAttribute((const void*)sparse_conv_mfma224,
                              hipFuncAttributeMaxDynamicSharedMemorySize, 131072);
    sparse_conv_mfma224<<<dim3(448), dim3(512), 131072, stream>>>(wd, xp, out);
}